// Round 3
// baseline (1367.957 us; speedup 1.0000x reference)
//
#include <hip/hip_runtime.h>
#include <math.h>

#define BB 512
#define SS 2048
#define DD 19
#define HH 40
#define CH 32
#define NCH (SS / CH)   // 64
#define RSTR 44         // ring row stride floats (176B, 16B aligned)
#define XGS 160         // xg row stride floats
#define XSTR 20         // padded row stride for x / W_ih (80B, 16B aligned)

__device__ __forceinline__ float gate_act(float a, float mulk) {
    // mulk=1: sigmoid(a); mulk=2: tanh(a).  res = 1 - mulk/(exp(mulk*a)+1). NaN-free.
    float e = __expf(a * mulk);
    float r = __builtin_amdgcn_rcpf(e + 1.0f);
    return fmaf(-mulk, r, 1.0f);
}
__device__ __forceinline__ float tanh_fast(float x) {
    float e = __expf(2.0f * x);
    float r = __builtin_amdgcn_rcpf(e + 1.0f);
    return fmaf(-2.0f, r, 1.0f);
}
__device__ __forceinline__ float sigm_fast(float x) {
    float e = __expf(x);
    float r = __builtin_amdgcn_rcpf(e + 1.0f);
    return fmaf(-1.0f, r, 1.0f);
}

__global__ __launch_bounds__(512, 2)
void lstm_fused(const float* __restrict__ x,
                const float* __restrict__ W_ih,
                const float* __restrict__ W_hh,
                const float* __restrict__ b_ih,
                const float* __restrict__ b_hh,
                const float* __restrict__ ln_g,
                const float* __restrict__ ln_b,
                const float* __restrict__ W1,
                const float* __restrict__ b1,
                const float* __restrict__ W2,
                const float* __restrict__ b2,
                const float* __restrict__ Wo,
                const float* __restrict__ bo,
                const float* __restrict__ log_thr,
                float* __restrict__ out) {
    // [batch-in-block][dbuf][step][...]
    __shared__ __align__(16) float s_xg[2][2][CH][XGS];     // 80 KB
    __shared__ __align__(16) float s_ring[2][2][CH][RSTR];  // 22 KB
    __shared__ __align__(16) float s_res[2][CH][RSTR];      // 11 KB
    __shared__ __align__(16) float s_x[2][CH][XSTR];        // 5 KB
    __shared__ __align__(16) float s_W1[HH * HH];           // 6.4 KB
    __shared__ __align__(16) float s_W2[HH * HH];           // 6.4 KB
    __shared__ __align__(16) float s_Wih[4 * HH][XSTR];     // 12.8 KB
    __shared__ float s_lng[HH], s_lnb[HH], s_Wo[HH], s_b1[HH], s_b2[HH];

    const int tid = threadIdx.x;
    const int lane = tid & 63;
    const int wave = tid >> 6;
    const int g = lane & 3;       // gate index within quad
    const int j = lane >> 2;      // unit-within-phase
    const bool isg0 = (g == 0);
    const float mulk = (g == 2) ? 2.0f : 1.0f;  // gate 2 = g~ -> tanh

    // ---- cooperative staging of shared weights ----
    for (int i = tid; i < HH * HH; i += 512) { s_W1[i] = W1[i]; s_W2[i] = W2[i]; }
    for (int i = tid; i < 4 * HH * DD; i += 512) { s_Wih[i / DD][i % DD] = W_ih[i]; }
    if (tid < HH) {
        s_lng[tid] = ln_g[tid]; s_lnb[tid] = ln_b[tid]; s_Wo[tid] = Wo[tid];
        s_b1[tid] = b1[tid]; s_b2[tid] = b2[tid];
    }

    const float bo0 = bo[0];
    const float thrv = expf(log_thr[0]);

    // ---- producer persistent state (waves 0,1) ----
    float whh[3][HH];
    float creg[3] = {0.f, 0.f, 0.f};
    float hreg[3] = {0.f, 0.f, 0.f};
    if (wave < 2) {
#pragma unroll
        for (int p = 0; p < 3; ++p) {
            bool ok = (p < 2) || (lane < 32);
            int u = 16 * p + j;
            int r = ok ? (g * HH + u) : 0;
#pragma unroll
            for (int k = 0; k < HH; ++k)
                whh[p][k] = ok ? W_hh[r * HH + k] : 0.0f;
        }
        // zero initial h: "row CH-1 of buffer 1" is read at ch=0,t=0
        if (lane < HH) s_ring[wave][1][CH - 1][lane] = 0.0f;
    }

    // ---- xg-wave persistent biases (waves 6,7) ----
    float bsum[3] = {0.f, 0.f, 0.f};
    if (wave >= 6) {
#pragma unroll
        for (int p = 0; p < 3; ++p) {
            int jj2 = (p == 2) ? ((lane & 31) >> 2) : j;
            int r = g * HH + 16 * p + jj2;
            bsum[p] = b_ih[r] + b_hh[r];
        }
    }

    // ================= role bodies =================
    auto produce = [&](int ch) {
        const int bb = wave;
        float (*xgbuf)[XGS] = s_xg[bb][ch & 1];
        float (*ringb)[RSTR] = s_ring[bb][ch & 1];
        const float* prevrow = s_ring[bb][(ch & 1) ^ 1][CH - 1];
#pragma unroll 1
        for (int t = 0; t < CH; ++t) {
            const float* hrow = (t == 0) ? prevrow : ringb[t - 1];
            const float4* h4 = (const float4*)hrow;
            float a0a = xgbuf[t][lane], a0b = 0.f;
            float a1a = xgbuf[t][64 + lane], a1b = 0.f;
            float a2a = xgbuf[t][128 + (lane & 31)], a2b = 0.f;
#pragma unroll
            for (int q = 0; q < 10; ++q) {
                float4 hq = h4[q];
                a0a = fmaf(hq.x, whh[0][4 * q + 0], a0a);
                a0b = fmaf(hq.y, whh[0][4 * q + 1], a0b);
                a0a = fmaf(hq.z, whh[0][4 * q + 2], a0a);
                a0b = fmaf(hq.w, whh[0][4 * q + 3], a0b);
                a1a = fmaf(hq.x, whh[1][4 * q + 0], a1a);
                a1b = fmaf(hq.y, whh[1][4 * q + 1], a1b);
                a1a = fmaf(hq.z, whh[1][4 * q + 2], a1a);
                a1b = fmaf(hq.w, whh[1][4 * q + 3], a1b);
                a2a = fmaf(hq.x, whh[2][4 * q + 0], a2a);
                a2b = fmaf(hq.y, whh[2][4 * q + 1], a2b);
                a2a = fmaf(hq.z, whh[2][4 * q + 2], a2a);
                a2b = fmaf(hq.w, whh[2][4 * q + 3], a2b);
            }
            float av0 = gate_act(a0a + a0b, mulk);
            float av1 = gate_act(a1a + a1b, mulk);
            float av2 = gate_act(a2a + a2b, mulk);
#pragma unroll
            for (int p = 0; p < 3; ++p) {
                float av = (p == 0) ? av0 : (p == 1) ? av1 : av2;
                float bv = __shfl_xor(av, 1);
                float cv = __shfl_xor(av, 2);
                float dv = __shfl_xor(bv, 2);
                // lane 4j+0: av=i, bv=f, cv=g~, dv=o (all pre-activated)
                if (isg0 && (p < 2 || lane < 32)) {
                    creg[p] = fmaf(bv, creg[p], av * cv);
                    float th = tanh_fast(creg[p]);
                    float hvv = dv * th;
                    hreg[p] = hvv;
                    ringb[t][16 * p + j] = hvv;
                }
            }
        }
    };

    auto compute_xg = [&](int ch) {
        const int bb = wave - 6;
        const int b2 = 2 * (int)blockIdx.x + bb;
        float (*xgbuf)[XGS] = s_xg[bb][ch & 1];
        // stage x chunk (coalesced)
        const float* xp = x + ((size_t)b2 * SS + (size_t)ch * CH) * DD;
        for (int i = lane; i < CH * DD; i += 64)
            s_x[bb][i / DD][i % DD] = xp[i];
        asm volatile("s_waitcnt lgkmcnt(0)" ::: "memory");
        const int col2 = 128 + (lane & 31);
        const int jj2 = (lane & 31) >> 2;
#pragma unroll 1
        for (int t = 0; t < CH; ++t) {
            float xv[20];
            const float4* xr = (const float4*)&s_x[bb][t][0];
#pragma unroll
            for (int q = 0; q < 5; ++q) {
                float4 f = xr[q];
                xv[4 * q] = f.x; xv[4 * q + 1] = f.y; xv[4 * q + 2] = f.z; xv[4 * q + 3] = f.w;
            }
#pragma unroll
            for (int p = 0; p < 3; ++p) {
                int jr = (p == 2) ? jj2 : j;
                int r = g * HH + 16 * p + jr;
                const float4* wr = (const float4*)&s_Wih[r][0];
                float aa = bsum[p], ab = 0.f;
#pragma unroll
                for (int q = 0; q < 5; ++q) {
                    float4 w4 = wr[q];
                    aa = fmaf(w4.x, xv[4 * q], aa);
                    if (4 * q + 1 < DD) ab = fmaf(w4.y, xv[4 * q + 1], ab);
                    if (4 * q + 2 < DD) aa = fmaf(w4.z, xv[4 * q + 2], aa);
                    if (4 * q + 3 < DD) ab = fmaf(w4.w, xv[4 * q + 3], ab);
                }
                if (p < 2)
                    xgbuf[t][p * 64 + lane] = aa + ab;
                else if (lane < 32)
                    xgbuf[t][col2] = aa + ab;
            }
        }
    };

    auto consume = [&](int ch) {
        const int bb = wave - 2;
        const int b2 = 2 * (int)blockIdx.x + bb;
        const int s = lane >> 1;
        const int half = lane & 1;
        const float* row = s_ring[bb][ch & 1][s];
        float* resr = s_res[bb][s];
        float hv[HH];
        const float4* r4 = (const float4*)row;
#pragma unroll
        for (int q = 0; q < 10; ++q) {
            float4 f = r4[q];
            hv[4 * q] = f.x; hv[4 * q + 1] = f.y; hv[4 * q + 2] = f.z; hv[4 * q + 3] = f.w;
        }
        float m0 = 0.f, m1 = 0.f, q0 = 0.f, q1 = 0.f;
#pragma unroll
        for (int k = 0; k < HH; k += 2) {
            m0 += hv[k]; m1 += hv[k + 1];
            q0 = fmaf(hv[k], hv[k], q0); q1 = fmaf(hv[k + 1], hv[k + 1], q1);
        }
        float mu = (m0 + m1) * (1.0f / HH);
        float var = (q0 + q1) * (1.0f / HH) - mu * mu;
        float inv = 1.0f / sqrtf(var + 1e-5f);
#pragma unroll
        for (int k = 0; k < HH; ++k)
            hv[k] = fmaf((hv[k] - mu) * inv, s_lng[k], s_lnb[k]);  // hv := ln
        float part = 0.f;
#pragma unroll
        for (int k = 0; k < 20; ++k) {
            int kk = half * 20 + k;
            part = fmaf(sigm_fast(hv[kk]), s_Wo[kk], part);
        }
        float r1v[20];
#pragma unroll 2
        for (int jj = 0; jj < 20; ++jj) {
            int jrow = half * 20 + jj;
            const float4* wr = (const float4*)&s_W1[jrow * HH];
            float aa = s_b1[jrow], ab = 0.f;
#pragma unroll
            for (int q = 0; q < 10; ++q) {
                float4 w4 = wr[q];
                aa = fmaf(w4.x, hv[4 * q], aa); ab = fmaf(w4.y, hv[4 * q + 1], ab);
                aa = fmaf(w4.z, hv[4 * q + 2], aa); ab = fmaf(w4.w, hv[4 * q + 3], ab);
            }
            float r1 = tanh_fast(aa + ab);
            r1v[jj] = r1;
            resr[jrow] = r1;
        }
        asm volatile("s_waitcnt lgkmcnt(0)" ::: "memory");
        float rr[HH];
        {
            const float4* o4 = (const float4*)&resr[(1 - half) * 20];
#pragma unroll
            for (int q = 0; q < 5; ++q) {
                float4 f = o4[q];
                int base = (1 - half) * 20 + 4 * q;
                rr[base] = f.x; rr[base + 1] = f.y; rr[base + 2] = f.z; rr[base + 3] = f.w;
            }
#pragma unroll
            for (int k = 0; k < 20; ++k) rr[half * 20 + k] = r1v[k];
        }
#pragma unroll 2
        for (int jj = 0; jj < 20; ++jj) {
            int jrow = half * 20 + jj;
            const float4* wr = (const float4*)&s_W2[jrow * HH];
            float aa = s_b2[jrow], ab = 0.f;
#pragma unroll
            for (int q = 0; q < 10; ++q) {
                float4 w4 = wr[q];
                aa = fmaf(w4.x, rr[4 * q], aa); ab = fmaf(w4.y, rr[4 * q + 1], ab);
                aa = fmaf(w4.z, rr[4 * q + 2], aa); ab = fmaf(w4.w, rr[4 * q + 3], ab);
            }
            float r2 = tanh_fast(aa + ab);
            part = fmaf(r2, s_Wo[jrow], part);
        }
        float tot = part + __shfl_xor(part, 1) + bo0;
        float raw = tanh_fast(tot);
        if (half == 0) {
            float sg = (fabsf(raw) >= thrv) ? raw : 0.0f;
            out[(size_t)b2 * SS + (size_t)ch * CH + s] = sg;
        }
    };

    // ================= schedule =================
    __syncthreads();  // staging visible
    if (wave >= 6) compute_xg(0);
    __syncthreads();

    for (int ph = 0; ph <= NCH; ++ph) {
        if (wave < 2) {
            if (ph < NCH) produce(ph);
        } else if (wave == 2 || wave == 3) {
            if (ph >= 1) consume(ph - 1);
        } else if (wave >= 6) {
            if (ph + 1 < NCH) compute_xg(ph + 1);
        }
        __syncthreads();
    }

    // ---- final states + threshold scalar ----
    if (wave < 2 && isg0) {
        int b2 = 2 * (int)blockIdx.x + wave;
        size_t baseh = (size_t)BB * SS + (size_t)b2 * HH;
        size_t basec = (size_t)BB * SS + (size_t)BB * HH + (size_t)b2 * HH;
        out[baseh + j] = hreg[0];
        out[baseh + 16 + j] = hreg[1];
        out[basec + j] = creg[0];
        out[basec + 16 + j] = creg[1];
        if (lane < 32) {
            out[baseh + 32 + j] = hreg[2];
            out[basec + 32 + j] = creg[2];
        }
    }
    if (blockIdx.x == 0 && tid == 0) {
        out[(size_t)BB * SS + 2 * (size_t)BB * HH] = thrv;
    }
}

extern "C" void kernel_launch(void* const* d_in, const int* in_sizes, int n_in,
                              void* d_out, int out_size, void* d_ws, size_t ws_size,
                              hipStream_t stream) {
    const float* x    = (const float*)d_in[0];
    const float* W_ih = (const float*)d_in[1];
    const float* W_hh = (const float*)d_in[2];
    const float* b_ih = (const float*)d_in[3];
    const float* b_hh = (const float*)d_in[4];
    const float* ln_g = (const float*)d_in[5];
    const float* ln_b = (const float*)d_in[6];
    const float* W1   = (const float*)d_in[7];
    const float* b1   = (const float*)d_in[8];
    const float* W2   = (const float*)d_in[9];
    const float* b2   = (const float*)d_in[10];
    const float* Wo   = (const float*)d_in[11];
    const float* bo   = (const float*)d_in[12];
    const float* lt   = (const float*)d_in[13];
    float* out = (float*)d_out;

    lstm_fused<<<dim3(BB / 2), dim3(512), 0, stream>>>(
        x, W_ih, W_hh, b_ih, b_hh, ln_g, ln_b, W1, b1, W2, b2, Wo, bo, lt, out);
}